// Round 1
// baseline (2478.408 us; speedup 1.0000x reference)
//
#include <hip/hip_runtime.h>
#include <hip/hip_bf16.h>

#define NPTS 131072
#define KCL  1024
#define DD   256

typedef __bf16 bf16x8 __attribute__((ext_vector_type(8)));
typedef __bf16 bf16x4 __attribute__((ext_vector_type(4)));
typedef float  f32x4  __attribute__((ext_vector_type(4)));

// out layout: [0] = mean, [1 .. K*D] = bins, [1+K*D .. 1+K*D+K) = nums
__global__ __launch_bounds__(256) void init_out_kernel(const float* __restrict__ bins_in,
                                                       const float* __restrict__ nums_in,
                                                       float* __restrict__ out) {
    int i = blockIdx.x * 256 + threadIdx.x;
    if (i == 0) out[0] = 0.0f;
    if (i < KCL * DD) out[1 + i] = bins_in[i];
    if (i < KCL) out[1 + KCL * DD + i] = nums_in[i];
}

// one wave per codebook row: convert to bf16 into ws, compute fp32 c_sq
__global__ __launch_bounds__(256) void prep_cb_kernel(const float* __restrict__ cb,
                                                      __bf16* __restrict__ cbh,
                                                      float* __restrict__ csq) {
    int gid  = blockIdx.x * 256 + threadIdx.x;
    int row  = gid >> 6;
    int lane = threadIdx.x & 63;
    float4 v = *reinterpret_cast<const float4*>(cb + (size_t)row * DD + lane * 4);
    bf16x4 h;
    h[0] = (__bf16)v.x; h[1] = (__bf16)v.y; h[2] = (__bf16)v.z; h[3] = (__bf16)v.w;
    *reinterpret_cast<bf16x4*>(cbh + (size_t)row * DD + lane * 4) = h;
    float ss = v.x * v.x + v.y * v.y + v.z * v.z + v.w * v.w;
#pragma unroll
    for (int m = 1; m < 64; m <<= 1) ss += __shfl_xor(ss, m, 64);
    if (lane == 0) csq[row] = ss;
}

// main: 256 threads = 4 waves, each wave owns 32 points; loops all 1024 clusters
__global__ __launch_bounds__(256, 2) void kmeans_kernel(const float* __restrict__ x,
                                                        const __bf16* __restrict__ cbh,
                                                        const float* __restrict__ csq,
                                                        float* __restrict__ out) {
    __shared__ int bucket_s[128];
    const int lane = threadIdx.x & 63;
    const int wid  = threadIdx.x >> 6;
    const int l15  = lane & 15;
    const int lg   = lane >> 4;               // 0..3 -> k-chunk group
    const int rowbase = blockIdx.x * 128 + wid * 32;

    // ---- load x tile as bf16 a-frags (held in regs), fp32 x_sq on the fly ----
    bf16x8 A[2][8];
    float xsq_e[2][4];
#pragma unroll
    for (int rt = 0; rt < 2; ++rt) {
        const float* xr = x + (size_t)(rowbase + rt * 16 + l15) * DD + lg * 8;
        float ss = 0.0f;
#pragma unroll
        for (int t = 0; t < 8; ++t) {
            float4 lo = *reinterpret_cast<const float4*>(xr + t * 32);
            float4 hi = *reinterpret_cast<const float4*>(xr + t * 32 + 4);
            ss += lo.x * lo.x + lo.y * lo.y + lo.z * lo.z + lo.w * lo.w;
            ss += hi.x * hi.x + hi.y * hi.y + hi.z * hi.z + hi.w * hi.w;
            bf16x8 a;
            a[0] = (__bf16)lo.x; a[1] = (__bf16)lo.y; a[2] = (__bf16)lo.z; a[3] = (__bf16)lo.w;
            a[4] = (__bf16)hi.x; a[5] = (__bf16)hi.y; a[6] = (__bf16)hi.z; a[7] = (__bf16)hi.w;
            A[rt][t] = a;
        }
        // full x_sq for row (rt*16 + l15): sum the 4 lane-groups
        ss += __shfl_xor(ss, 16, 64);
        ss += __shfl_xor(ss, 32, 64);
        // remap to C/D row ownership: this lane's output rows are rt*16 + lg*4 + r
#pragma unroll
        for (int r = 0; r < 4; ++r) xsq_e[rt][r] = __shfl(ss, lg * 4 + r, 64);
    }

    float minv[2][4];
    int   mini[2][4];
    float ssum = 0.0f;
#pragma unroll
    for (int rt = 0; rt < 2; ++rt)
#pragma unroll
        for (int r = 0; r < 4; ++r) { minv[rt][r] = 3.4e38f; mini[rt][r] = 0; }

    const __bf16* cbl = cbh + (size_t)l15 * DD + lg * 8;  // cluster l15 of tile 0

    bf16x8 Ba[8], Bb[8];
#pragma unroll
    for (int t = 0; t < 8; ++t) Ba[t] = *reinterpret_cast<const bf16x8*>(cbl + t * 32);

    auto compute_tile = [&](const bf16x8 (&B)[8], int kt) {
        f32x4 acc0 = {0.f, 0.f, 0.f, 0.f}, acc1 = {0.f, 0.f, 0.f, 0.f};
#pragma unroll
        for (int t = 0; t < 8; ++t) {
            acc0 = __builtin_amdgcn_mfma_f32_16x16x32_bf16(A[0][t], B[t], acc0, 0, 0, 0);
            acc1 = __builtin_amdgcn_mfma_f32_16x16x32_bf16(A[1][t], B[t], acc1, 0, 0, 0);
        }
        const int  colb = kt * 16 + l15;
        const float cs  = csq[colb];
#pragma unroll
        for (int r = 0; r < 4; ++r) {
            float d2a = fmaf(-2.0f, acc0[r], xsq_e[0][r] + cs);
            ssum += sqrtf(fmaxf(d2a, 0.0f));
            if (d2a < minv[0][r]) { minv[0][r] = d2a; mini[0][r] = colb; }
            float d2b = fmaf(-2.0f, acc1[r], xsq_e[1][r] + cs);
            ssum += sqrtf(fmaxf(d2b, 0.0f));
            if (d2b < minv[1][r]) { minv[1][r] = d2b; mini[1][r] = colb; }
        }
    };

    for (int kt = 0; kt < 64; kt += 2) {
        const __bf16* cbn = cbl + 16 * DD;
#pragma unroll
        for (int t = 0; t < 8; ++t) Bb[t] = *reinterpret_cast<const bf16x8*>(cbn + t * 32);
        compute_tile(Ba, kt);
        cbl += 32 * DD;
        if (kt + 2 < 64) {
#pragma unroll
            for (int t = 0; t < 8; ++t) Ba[t] = *reinterpret_cast<const bf16x8*>(cbl + t * 32);
        }
        compute_tile(Bb, kt + 1);
    }

    // ---- per-row argmin across the 16 lanes of each group (cols mod 16) ----
#pragma unroll
    for (int rt = 0; rt < 2; ++rt)
#pragma unroll
        for (int r = 0; r < 4; ++r) {
            float v = minv[rt][r];
            int   i = mini[rt][r];
#pragma unroll
            for (int m = 1; m <= 8; m <<= 1) {
                float ov = __shfl_xor(v, m, 64);
                int   oi = __shfl_xor(i, m, 64);
                if (ov < v || (ov == v && oi < i)) { v = ov; i = oi; }
            }
            if (l15 == 0) bucket_s[wid * 32 + rt * 16 + lg * 4 + r] = i;
        }
    __syncthreads();

    // ---- scatter: bins += x (from bf16 frags), nums += 1 ----
    float* bins = out + 1;
    float* nums = out + 1 + KCL * DD;
#pragma unroll
    for (int rt = 0; rt < 2; ++rt) {
        int b = bucket_s[wid * 32 + rt * 16 + l15];
        float* br = bins + (size_t)b * DD + lg * 8;
#pragma unroll
        for (int t = 0; t < 8; ++t)
#pragma unroll
            for (int j = 0; j < 8; ++j)
                atomicAdd(br + t * 32 + j, (float)A[rt][t][j]);
    }
    if (lane < 32) {
        int rt = lane >> 4;
        int b  = bucket_s[wid * 32 + rt * 16 + l15];
        atomicAdd(nums + b, 1.0f);
    }

    // ---- mean partial: sum of sqrt over this wave's 32x1024 dists ----
#pragma unroll
    for (int m = 1; m < 64; m <<= 1) ssum += __shfl_xor(ssum, m, 64);
    if (lane == 0) atomicAdd(out, ssum * 7.4505805969238281e-9f);  // 1/2^27 exact
}

extern "C" void kernel_launch(void* const* d_in, const int* in_sizes, int n_in,
                              void* d_out, int out_size, void* d_ws, size_t ws_size,
                              hipStream_t stream) {
    const float* x    = (const float*)d_in[0];
    const float* cb   = (const float*)d_in[1];
    const float* bins = (const float*)d_in[2];
    const float* nums = (const float*)d_in[3];
    float* out = (float*)d_out;

    __bf16* cbh = (__bf16*)d_ws;                                   // 512 KB
    float*  csq = (float*)((char*)d_ws + KCL * DD * sizeof(__bf16)); // 4 KB

    init_out_kernel<<<(1 + KCL * DD + KCL + 255) / 256, 256, 0, stream>>>(bins, nums, out);
    prep_cb_kernel<<<KCL / 4, 256, 0, stream>>>(cb, cbh, csq);
    kmeans_kernel<<<NPTS / 128, 256, 0, stream>>>(x, cbh, csq, out);
}

// Round 2
// 526.729 us; speedup vs baseline: 4.7053x; 4.7053x over previous
//
#include <hip/hip_runtime.h>
#include <hip/hip_bf16.h>

#define NPTS 131072
#define KCL  1024
#define DD   256

typedef __bf16 bf16x8 __attribute__((ext_vector_type(8)));
typedef __bf16 bf16x4 __attribute__((ext_vector_type(4)));
typedef float  f32x4  __attribute__((ext_vector_type(4)));

// out layout: [0] = mean, [1 .. K*D] = bins, [1+K*D .. 1+K*D+K) = nums
__global__ __launch_bounds__(256) void init_out_kernel(const float* __restrict__ bins_in,
                                                       const float* __restrict__ nums_in,
                                                       float* __restrict__ out) {
    int i = blockIdx.x * 256 + threadIdx.x;
    if (i == 0) out[0] = 0.0f;
    if (i < KCL * DD) out[1 + i] = bins_in[i];
    if (i < KCL) out[1 + KCL * DD + i] = nums_in[i];
}

// one wave per codebook row: convert to bf16 into ws, compute fp32 c_sq
__global__ __launch_bounds__(256) void prep_cb_kernel(const float* __restrict__ cb,
                                                      __bf16* __restrict__ cbh,
                                                      float* __restrict__ csq) {
    int gid  = blockIdx.x * 256 + threadIdx.x;
    int row  = gid >> 6;
    int lane = threadIdx.x & 63;
    float4 v = *reinterpret_cast<const float4*>(cb + (size_t)row * DD + lane * 4);
    bf16x4 h;
    h[0] = (__bf16)v.x; h[1] = (__bf16)v.y; h[2] = (__bf16)v.z; h[3] = (__bf16)v.w;
    *reinterpret_cast<bf16x4*>(cbh + (size_t)row * DD + lane * 4) = h;
    float ss = v.x * v.x + v.y * v.y + v.z * v.z + v.w * v.w;
#pragma unroll
    for (int m = 1; m < 64; m <<= 1) ss += __shfl_xor(ss, m, 64);
    if (lane == 0) csq[row] = ss;
}

// main: 256 threads = 4 waves, each wave owns 32 points; loops all 1024 clusters.
// Outputs: bucket[i] (argmin cluster per point) + mean partial atomics.
__global__ __launch_bounds__(256, 2) void kmeans_kernel(const float* __restrict__ x,
                                                        const __bf16* __restrict__ cbh,
                                                        const float* __restrict__ csq,
                                                        int* __restrict__ bucketg,
                                                        float* __restrict__ out) {
    __shared__ int bucket_s[128];
    const int lane = threadIdx.x & 63;
    const int wid  = threadIdx.x >> 6;
    const int l15  = lane & 15;
    const int lg   = lane >> 4;               // 0..3 -> k-chunk group
    const int rowbase = blockIdx.x * 128 + wid * 32;

    // ---- load x tile as bf16 a-frags (held in regs), fp32 x_sq on the fly ----
    bf16x8 A[2][8];
    float xsq_e[2][4];
#pragma unroll
    for (int rt = 0; rt < 2; ++rt) {
        const float* xr = x + (size_t)(rowbase + rt * 16 + l15) * DD + lg * 8;
        float ss = 0.0f;
#pragma unroll
        for (int t = 0; t < 8; ++t) {
            float4 lo = *reinterpret_cast<const float4*>(xr + t * 32);
            float4 hi = *reinterpret_cast<const float4*>(xr + t * 32 + 4);
            ss += lo.x * lo.x + lo.y * lo.y + lo.z * lo.z + lo.w * lo.w;
            ss += hi.x * hi.x + hi.y * hi.y + hi.z * hi.z + hi.w * hi.w;
            bf16x8 a;
            a[0] = (__bf16)lo.x; a[1] = (__bf16)lo.y; a[2] = (__bf16)lo.z; a[3] = (__bf16)lo.w;
            a[4] = (__bf16)hi.x; a[5] = (__bf16)hi.y; a[6] = (__bf16)hi.z; a[7] = (__bf16)hi.w;
            A[rt][t] = a;
        }
        // full x_sq for row (rt*16 + l15): sum the 4 lane-groups
        ss += __shfl_xor(ss, 16, 64);
        ss += __shfl_xor(ss, 32, 64);
        // remap to C/D row ownership: this lane's output rows are rt*16 + lg*4 + r
#pragma unroll
        for (int r = 0; r < 4; ++r) xsq_e[rt][r] = __shfl(ss, lg * 4 + r, 64);
    }

    float minv[2][4];
    int   mini[2][4];
    float ssum = 0.0f;
#pragma unroll
    for (int rt = 0; rt < 2; ++rt)
#pragma unroll
        for (int r = 0; r < 4; ++r) { minv[rt][r] = 3.4e38f; mini[rt][r] = 0; }

    const __bf16* cbl = cbh + (size_t)l15 * DD + lg * 8;  // cluster l15 of tile 0

    bf16x8 Ba[8], Bb[8];
#pragma unroll
    for (int t = 0; t < 8; ++t) Ba[t] = *reinterpret_cast<const bf16x8*>(cbl + t * 32);

    auto compute_tile = [&](const bf16x8 (&B)[8], int kt) {
        f32x4 acc0 = {0.f, 0.f, 0.f, 0.f}, acc1 = {0.f, 0.f, 0.f, 0.f};
#pragma unroll
        for (int t = 0; t < 8; ++t) {
            acc0 = __builtin_amdgcn_mfma_f32_16x16x32_bf16(A[0][t], B[t], acc0, 0, 0, 0);
            acc1 = __builtin_amdgcn_mfma_f32_16x16x32_bf16(A[1][t], B[t], acc1, 0, 0, 0);
        }
        const int  colb = kt * 16 + l15;
        const float cs  = csq[colb];
#pragma unroll
        for (int r = 0; r < 4; ++r) {
            float d2a = fmaf(-2.0f, acc0[r], xsq_e[0][r] + cs);
            ssum += sqrtf(fmaxf(d2a, 0.0f));
            if (d2a < minv[0][r]) { minv[0][r] = d2a; mini[0][r] = colb; }
            float d2b = fmaf(-2.0f, acc1[r], xsq_e[1][r] + cs);
            ssum += sqrtf(fmaxf(d2b, 0.0f));
            if (d2b < minv[1][r]) { minv[1][r] = d2b; mini[1][r] = colb; }
        }
    };

    for (int kt = 0; kt < 64; kt += 2) {
        const __bf16* cbn = cbl + 16 * DD;
#pragma unroll
        for (int t = 0; t < 8; ++t) Bb[t] = *reinterpret_cast<const bf16x8*>(cbn + t * 32);
        compute_tile(Ba, kt);
        cbl += 32 * DD;
        if (kt + 2 < 64) {
#pragma unroll
            for (int t = 0; t < 8; ++t) Ba[t] = *reinterpret_cast<const bf16x8*>(cbl + t * 32);
        }
        compute_tile(Bb, kt + 1);
    }

    // ---- per-row argmin across the 16 lanes of each group (cols mod 16) ----
#pragma unroll
    for (int rt = 0; rt < 2; ++rt)
#pragma unroll
        for (int r = 0; r < 4; ++r) {
            float v = minv[rt][r];
            int   i = mini[rt][r];
#pragma unroll
            for (int m = 1; m <= 8; m <<= 1) {
                float ov = __shfl_xor(v, m, 64);
                int   oi = __shfl_xor(i, m, 64);
                if (ov < v || (ov == v && oi < i)) { v = ov; i = oi; }
            }
            if (l15 == 0) bucket_s[wid * 32 + rt * 16 + lg * 4 + r] = i;
        }
    __syncthreads();

    // ---- write this block's 128 bucket assignments ----
    if (threadIdx.x < 128) bucketg[blockIdx.x * 128 + threadIdx.x] = bucket_s[threadIdx.x];

    // ---- mean partial: sum of sqrt over this wave's 32x1024 dists ----
#pragma unroll
    for (int m = 1; m < 64; m <<= 1) ssum += __shfl_xor(ssum, m, 64);
    if (lane == 0) atomicAdd(out, ssum * 7.4505805969238281e-9f);  // 1/2^27 exact
}

// one block per cluster: scan buckets, gather matching x rows, owner-writes bins/nums
__global__ __launch_bounds__(256) void accum_kernel(const float* __restrict__ x,
                                                    const int* __restrict__ bucket,
                                                    float* __restrict__ out) {
    const int c   = blockIdx.x;
    const int tid = threadIdx.x;     // == dim index (DD == 256)
    __shared__ int list[8192];
    __shared__ int cnt;
    float acc0 = 0.f, acc1 = 0.f, acc2 = 0.f, acc3 = 0.f;
    int total = 0;

    for (int chunk = 0; chunk < NPTS; chunk += 8192) {
        if (tid == 0) cnt = 0;
        __syncthreads();
        const int4* bp = reinterpret_cast<const int4*>(bucket + chunk);
#pragma unroll 2
        for (int v = tid; v < 2048; v += 256) {
            int4 b4 = bp[v];
            int base = chunk + v * 4;
            if (b4.x == c) list[atomicAdd(&cnt, 1)] = base;
            if (b4.y == c) list[atomicAdd(&cnt, 1)] = base + 1;
            if (b4.z == c) list[atomicAdd(&cnt, 1)] = base + 2;
            if (b4.w == c) list[atomicAdd(&cnt, 1)] = base + 3;
        }
        __syncthreads();
        const int n = cnt;
        total += n;
        int j = 0;
        for (; j + 4 <= n; j += 4) {
            acc0 += x[(size_t)list[j]     * DD + tid];
            acc1 += x[(size_t)list[j + 1] * DD + tid];
            acc2 += x[(size_t)list[j + 2] * DD + tid];
            acc3 += x[(size_t)list[j + 3] * DD + tid];
        }
        for (; j < n; ++j) acc0 += x[(size_t)list[j] * DD + tid];
        __syncthreads();
    }

    float* bins = out + 1;
    float* nums = out + 1 + KCL * DD;
    bins[(size_t)c * DD + tid] += (acc0 + acc1) + (acc2 + acc3);
    if (tid == 0) nums[c] += (float)total;
}

extern "C" void kernel_launch(void* const* d_in, const int* in_sizes, int n_in,
                              void* d_out, int out_size, void* d_ws, size_t ws_size,
                              hipStream_t stream) {
    const float* x    = (const float*)d_in[0];
    const float* cb   = (const float*)d_in[1];
    const float* bins = (const float*)d_in[2];
    const float* nums = (const float*)d_in[3];
    float* out = (float*)d_out;

    __bf16* cbh    = (__bf16*)d_ws;                                      // 512 KB
    float*  csq    = (float*)((char*)d_ws + KCL * DD * sizeof(__bf16));  // 4 KB
    int*    bucket = (int*)((char*)d_ws + KCL * DD * sizeof(__bf16) + KCL * sizeof(float)); // 512 KB

    init_out_kernel<<<(1 + KCL * DD + KCL + 255) / 256, 256, 0, stream>>>(bins, nums, out);
    prep_cb_kernel<<<KCL / 4, 256, 0, stream>>>(cb, cbh, csq);
    kmeans_kernel<<<NPTS / 128, 256, 0, stream>>>(x, cbh, csq, bucket, out);
    accum_kernel<<<KCL, 256, 0, stream>>>(x, bucket, out);
}